// Round 22
// baseline (492.014 us; speedup 1.0000x reference)
//
#include <hip/hip_runtime.h>

#define NN 50000      // nodes
#define NE 250000     // edges
#define DD 256        // feature dim
#define NREL 8        // relations
#define NL 3          // layers

#define NSRCB ((NN + 127) / 128)     // 391 src blocks
#define NBKT (NREL * NSRCB)          // 3128 sort buckets (rel, src>>7)

typedef __attribute__((ext_vector_type(8))) short short8;
typedef __attribute__((ext_vector_type(4))) float floatx4;
typedef __attribute__((ext_vector_type(2))) unsigned int u32x2;

#if __has_builtin(__builtin_amdgcn_global_load_lds)
#define GLOAD16(g, l) __builtin_amdgcn_global_load_lds( \
    (__attribute__((address_space(1))) void*)(void*)(g), \
    (__attribute__((address_space(3))) void*)(void*)(l), 16, 0, 0)
#else
#define GLOAD16(g, l) do { *(uint4*)(l) = *(const uint4*)(g); } while (0)
#endif

__device__ inline unsigned short f2bf(float f) {
    unsigned int u = __builtin_bit_cast(unsigned int, f);
    u += 0x7FFFu + ((u >> 16) & 1u);          // round-to-nearest-even
    return (unsigned short)(u >> 16);
}
__device__ inline float bf2f(unsigned short u) {
    unsigned int x = ((unsigned int)u) << 16;
    return __builtin_bit_cast(float, x);
}

// ================= sort / index building =================
__global__ void zero_ints(int* __restrict__ p, int n) {
    int i = blockIdx.x * blockDim.x + threadIdx.x;
    if (i < n) p[i] = 0;
}

__global__ void hist_bkt(const int* __restrict__ ei, const int* __restrict__ et,
                         int* __restrict__ bktCnt) {
    int e = blockIdx.x * blockDim.x + threadIdx.x;
    if (e < NE) atomicAdd(&bktCnt[et[e] * NSRCB + (ei[e] >> 7)], 1);
}

// ---- hierarchical exclusive scan: part-sums -> top scan -> local scan ----
__global__ __launch_bounds__(256)
void scan_part(const int* __restrict__ cnt, int n, int* __restrict__ blockSums) {
    __shared__ int ps[256];
    const int b = blockIdx.x, t = threadIdx.x;
    const int base = b * 1024 + t * 4;
    int s = 0;
#pragma unroll
    for (int j = 0; j < 4; ++j) s += (base + j < n) ? cnt[base + j] : 0;
    ps[t] = s;
    __syncthreads();
    for (int o = 128; o > 0; o >>= 1) {
        if (t < o) ps[t] += ps[t + o];
        __syncthreads();
    }
    if (t == 0) blockSums[b] = ps[0];
}

__global__ __launch_bounds__(256)
void scan_tops(const int* __restrict__ blockSums, int nb, int* __restrict__ blockOffs) {
    __shared__ int ps[256];
    const int t = threadIdx.x;
    ps[t] = (t < nb) ? blockSums[t] : 0;
    __syncthreads();
    for (int o = 1; o < 256; o <<= 1) {
        int x = (t >= o) ? ps[t - o] : 0;
        __syncthreads();
        ps[t] += x;
        __syncthreads();
    }
    blockOffs[t] = (t == 0) ? 0 : ps[t - 1];
}

__global__ __launch_bounds__(256)
void scan_local(const int* __restrict__ cnt, int n, int total,
                const int* __restrict__ blockOffs,
                int* __restrict__ offs, int* __restrict__ cur) {
    __shared__ int ps[256];
    const int b = blockIdx.x, t = threadIdx.x;
    const int base = b * 1024 + t * 4;
    int v[4];
#pragma unroll
    for (int j = 0; j < 4; ++j) v[j] = (base + j < n) ? cnt[base + j] : 0;
    int s = v[0] + v[1] + v[2] + v[3];
    ps[t] = s;
    __syncthreads();
    for (int o = 1; o < 256; o <<= 1) {
        int x = (t >= o) ? ps[t - o] : 0;
        __syncthreads();
        ps[t] += x;
        __syncthreads();
    }
    int run = blockOffs[b] + ((t == 0) ? 0 : ps[t - 1]);
#pragma unroll
    for (int j = 0; j < 4; ++j) {
        if (base + j < n) { offs[base + j] = run; cur[base + j] = run; run += v[j]; }
    }
    if (b == 0 && t == 0) offs[n] = total;
}

__global__ void mk_reloffs(const int* __restrict__ bktOff, int* __restrict__ relOffs) {
    const int t = threadIdx.x;
    if (t < NREL) relOffs[t] = bktOff[t * NSRCB];
    if (t == 0) relOffs[NREL] = NE;
}

__global__ void scatter_bkt(const int* __restrict__ ei, const int* __restrict__ et,
                            int* __restrict__ bktCur, int* __restrict__ ssrc,
                            int* __restrict__ sdst) {
    int e = blockIdx.x * blockDim.x + threadIdx.x;
    if (e < NE) {
        int s = ei[e];
        int p = atomicAdd(&bktCur[et[e] * NSRCB + (s >> 7)], 1);
        ssrc[p] = s;
        sdst[p] = ei[NE + e];
    }
}

__global__ void hist_dst(const int* __restrict__ sdst, int* __restrict__ dstCnt) {
    int p = blockIdx.x * blockDim.x + threadIdx.x;
    if (p < NE) atomicAdd(&dstCnt[sdst[p]], 1);
}

// message slot for each sorted edge: its position in dst-sorted order
__global__ void mk_mpos(const int* __restrict__ sdst, int* __restrict__ dstCur,
                        int* __restrict__ mpos) {
    int p = blockIdx.x * blockDim.x + threadIdx.x;
    if (p < NE) mpos[p] = atomicAdd(&dstCur[sdst[p]], 1);
}

// ============ weight transpose + fp32->bf16 (out[m][e][d] = in[m][d][e]) ============
__global__ void transpose_bf16(const float* __restrict__ src, unsigned short* __restrict__ dst) {
    __shared__ float t[32][33];
    const size_t mb = (size_t)blockIdx.x * DD * DD;
    const int d0 = blockIdx.y * 32, e0 = blockIdx.z * 32;
    const int tx = threadIdx.x, ty = threadIdx.y;
#pragma unroll
    for (int i = 0; i < 4; ++i)
        t[ty + 8 * i][tx] = src[mb + (size_t)(d0 + ty + 8 * i) * DD + e0 + tx];
    __syncthreads();
#pragma unroll
    for (int i = 0; i < 4; ++i)
        dst[mb + (size_t)(e0 + ty + 8 * i) * DD + d0 + tx] = f2bf(t[tx][ty + 8 * i]);
}

__global__ void conv_bf16(const float4* __restrict__ s, ushort4* __restrict__ d, int n4) {
    int i = blockIdx.x * blockDim.x + threadIdx.x;
    const int stride = gridDim.x * blockDim.x;
    for (; i < n4; i += stride) {
        float4 v = s[i];
        d[i] = make_ushort4(f2bf(v.x), f2bf(v.y), f2bf(v.z), f2bf(v.w));
    }
}

// fallback-path relu+convert
__global__ void relu_convert(float4* __restrict__ p, ushort4* __restrict__ xb, int n4) {
    int i = blockIdx.x * blockDim.x + threadIdx.x;
    const int stride = gridDim.x * blockDim.x;
    for (; i < n4; i += stride) {
        float4 v = p[i];
        v.x = v.x > 0.f ? v.x : 0.f;
        v.y = v.y > 0.f ? v.y : 0.f;
        v.z = v.z > 0.f ? v.z : 0.f;
        v.w = v.w > 0.f ? v.w : 0.f;
        p[i] = v;
        xb[i] = make_ushort4(f2bf(v.x), f2bf(v.y), f2bf(v.z), f2bf(v.w));
    }
}

// ---- root GEMM (MFMA), r13 row-major LDS staging, bf16 or fp32 epilogue ----
__global__ __launch_bounds__(256)
void root_gemm_r(const unsigned short* __restrict__ Xb, const unsigned short* __restrict__ WT,
                 const float* __restrict__ bias, float* __restrict__ Cf,
                 unsigned short* __restrict__ Cb, int useB)
{
    __shared__ unsigned short As[128][32];
    __shared__ unsigned short Bs[128][32];
    const int tid = threadIdx.x;
    const int lane = tid & 63;
    const int w = tid >> 6;
    const int wr = w >> 1, wc = w & 1;
    const int m0 = blockIdx.x * 128;
    const int n0 = blockIdx.y * 128;
    const int srow = tid >> 2;          // 0..63
    const int sq = tid & 3;             // 16B quarter of 64B k-slice

    floatx4 acc[4][4] = {};

    for (int kt = 0; kt < DD / 32; ++kt) {
        const int k0 = kt * 32;
        int r0 = min(m0 + srow, NN - 1);
        int r1 = min(m0 + srow + 64, NN - 1);
        GLOAD16(&Xb[(size_t)r0 * DD + k0 + sq * 8], &As[srow][sq * 8]);
        GLOAD16(&Xb[(size_t)r1 * DD + k0 + sq * 8], &As[srow + 64][sq * 8]);
        GLOAD16(&WT[(size_t)(n0 + srow) * DD + k0 + sq * 8], &Bs[srow][sq * 8]);
        GLOAD16(&WT[(size_t)(n0 + srow + 64) * DD + k0 + sq * 8], &Bs[srow + 64][sq * 8]);
        __syncthreads();
        short8 a[4], b[4];
#pragma unroll
        for (int mi = 0; mi < 4; ++mi)
            a[mi] = *(const short8*)&As[wr * 64 + mi * 16 + (lane & 15)][(lane >> 4) * 8];
#pragma unroll
        for (int ni = 0; ni < 4; ++ni)
            b[ni] = *(const short8*)&Bs[wc * 64 + ni * 16 + (lane & 15)][(lane >> 4) * 8];
#pragma unroll
        for (int mi = 0; mi < 4; ++mi)
#pragma unroll
            for (int ni = 0; ni < 4; ++ni)
                acc[mi][ni] = __builtin_amdgcn_mfma_f32_16x16x32_bf16(a[mi], b[ni], acc[mi][ni], 0, 0, 0);
        __syncthreads();
    }

    const int cq = lane >> 4;
    const int cn = lane & 15;
#pragma unroll
    for (int mi = 0; mi < 4; ++mi) {
#pragma unroll
        for (int q = 0; q < 4; ++q) {
            int row = m0 + wr * 64 + mi * 16 + cq * 4 + q;
            if (row < NN) {
#pragma unroll
                for (int ni = 0; ni < 4; ++ni) {
                    int col = n0 + wc * 64 + ni * 16 + cn;
                    float val = acc[mi][ni][q] + bias[col];
                    if (useB) Cb[(size_t)row * DD + col] = f2bf(val);
                    else      Cf[(size_t)row * DD + col] = val;
                }
            }
        }
    }
}

// ==== edge GEMM -> bf16 messages at dst-sorted slots ====
// r18 XCD-aware window mapping + NEW double-buffered LDS prefetch: next
// k-step's global_load_lds are issued BEFORE the current step's ds_read+MFMA,
// hiding gather latency under compute; one barrier per k-step instead of two.
__global__ __launch_bounds__(256)
void edge_msgs_m(const unsigned short* __restrict__ Xb, const unsigned short* __restrict__ WTl,
                 const int* __restrict__ ssrc, const int* __restrict__ mpos,
                 const int* __restrict__ relOffs, unsigned short* __restrict__ msgs)
{
    __shared__ unsigned short As[2][128][32];
    __shared__ unsigned short Bs[2][128][32];
    __shared__ int srcs[128];
    __shared__ int mposs[128];

    const int q0 = blockIdx.x;
    const int rel = (q0 >> 3) & 7;
    const int i = ((q0 >> 6) << 3) | (q0 & 7);
    const int s = relOffs[rel], e = relOffs[rel + 1];
    const int base = s + i * 128;
    if (base >= e) return;
    const int cnt = min(128, e - base);

    const int tid = threadIdx.x;
    if (tid < 128) {
        int idx = base + tid;
        srcs[tid] = (tid < cnt) ? ssrc[idx] : 0;
        mposs[tid] = (tid < cnt) ? mpos[idx] : 0;
    }
    __syncthreads();

    const unsigned short* WT = WTl + (size_t)rel * DD * DD;

    const int lane = tid & 63;
    const int w = tid >> 6;
    const int wr = w >> 1, wc = w & 1;
    const int n0 = blockIdx.y * 128;
    const int srow = tid >> 2;
    const int sq = tid & 3;

    // hoist gather rows to registers (stable across k-steps)
    const int r0 = srcs[srow];
    const int r1 = srcs[srow + 64];
    const unsigned short* xa0 = &Xb[(size_t)r0 * DD + sq * 8];
    const unsigned short* xa1 = &Xb[(size_t)r1 * DD + sq * 8];
    const unsigned short* wb0 = &WT[(size_t)(n0 + srow) * DD + sq * 8];
    const unsigned short* wb1 = &WT[(size_t)(n0 + srow + 64) * DD + sq * 8];

    // prologue: stage k-step 0 into buffer 0
    GLOAD16(xa0, &As[0][srow][sq * 8]);
    GLOAD16(xa1, &As[0][srow + 64][sq * 8]);
    GLOAD16(wb0, &Bs[0][srow][sq * 8]);
    GLOAD16(wb1, &Bs[0][srow + 64][sq * 8]);

    floatx4 acc[4][4] = {};

    for (int kt = 0; kt < DD / 32; ++kt) {
        const int cur = kt & 1;
        __syncthreads();   // buf[cur] loads landed; prior reads of buf[cur^1] done
        if (kt + 1 < DD / 32) {
            const int k0n = (kt + 1) * 32;
            GLOAD16(xa0 + k0n, &As[cur ^ 1][srow][sq * 8]);
            GLOAD16(xa1 + k0n, &As[cur ^ 1][srow + 64][sq * 8]);
            GLOAD16(wb0 + k0n, &Bs[cur ^ 1][srow][sq * 8]);
            GLOAD16(wb1 + k0n, &Bs[cur ^ 1][srow + 64][sq * 8]);
        }
        short8 a[4], b[4];
#pragma unroll
        for (int mi = 0; mi < 4; ++mi)
            a[mi] = *(const short8*)&As[cur][wr * 64 + mi * 16 + (lane & 15)][(lane >> 4) * 8];
#pragma unroll
        for (int ni = 0; ni < 4; ++ni)
            b[ni] = *(const short8*)&Bs[cur][wc * 64 + ni * 16 + (lane & 15)][(lane >> 4) * 8];
#pragma unroll
        for (int mi = 0; mi < 4; ++mi)
#pragma unroll
            for (int ni = 0; ni < 4; ++ni)
                acc[mi][ni] = __builtin_amdgcn_mfma_f32_16x16x32_bf16(a[mi], b[ni], acc[mi][ni], 0, 0, 0);
    }

    const int cq = lane >> 4;
    const int cn = lane & 15;
#pragma unroll
    for (int mi = 0; mi < 4; ++mi) {
#pragma unroll
        for (int q = 0; q < 4; ++q) {
            int slot = wr * 64 + mi * 16 + cq * 4 + q;
            if (slot < cnt) {
                size_t mrow = (size_t)mposs[slot] * DD + n0 + wc * 64;
#pragma unroll
                for (int ni = 0; ni < 4; ++ni)
                    msgs[mrow + ni * 16 + cn] = f2bf(acc[mi][ni][q]);
            }
        }
    }
}

// ======== combine: relu(rootb + sum msgs[contiguous, nt-streamed]); write xb/out ========
__global__ __launch_bounds__(256)
void combine4b(const unsigned short* __restrict__ msgs, const int* __restrict__ dstOffs,
               const unsigned short* __restrict__ rootb, const float* __restrict__ rootf,
               float* __restrict__ out, unsigned short* __restrict__ xb,
               int useRootB, int last)
{
    int v = blockIdx.x * 4 + (threadIdx.x >> 6);
    if (v >= NN) return;
    const int lane = threadIdx.x & 63;
    const size_t rb = (size_t)v * DD + lane * 4;
    float4 a;
    if (useRootB) {
        u32x2 r = *(const u32x2*)&rootb[rb];
        a.x = bf2f((unsigned short)(r.x & 0xffff));
        a.y = bf2f((unsigned short)(r.x >> 16));
        a.z = bf2f((unsigned short)(r.y & 0xffff));
        a.w = bf2f((unsigned short)(r.y >> 16));
    } else {
        a = *(const float4*)&rootf[rb];
    }
    const int b0 = dstOffs[v], b1 = dstOffs[v + 1];
    for (int k = b0; k < b1; ++k) {
        // non-temporal: msgs is a read-once 128MB stream; keep it out of L2/L3
        u32x2 m = __builtin_nontemporal_load((const u32x2*)&msgs[(size_t)k * DD + lane * 4]);
        a.x += bf2f((unsigned short)(m.x & 0xffff));
        a.y += bf2f((unsigned short)(m.x >> 16));
        a.z += bf2f((unsigned short)(m.y & 0xffff));
        a.w += bf2f((unsigned short)(m.y >> 16));
    }
    a.x = a.x > 0.f ? a.x : 0.f;
    a.y = a.y > 0.f ? a.y : 0.f;
    a.z = a.z > 0.f ? a.z : 0.f;
    a.w = a.w > 0.f ? a.w : 0.f;
    if (last) {
        *(float4*)&out[rb] = a;
    } else {
        *(ushort4*)&xb[rb] = make_ushort4(f2bf(a.x), f2bf(a.y), f2bf(a.z), f2bf(a.w));
    }
}

// ======== fallback: atomic-scatter edge GEMM (round-5 proven) ========
__global__ __launch_bounds__(256)
void edge_gemm_mfma(const unsigned short* __restrict__ Xb, const unsigned short* __restrict__ WTl,
                    const int* __restrict__ ssrc, const int* __restrict__ sdst,
                    const int* __restrict__ offsets, float* __restrict__ out)
{
    __shared__ unsigned short As[128][32];
    __shared__ unsigned short Bs[128][32];
    __shared__ int srcs[128];
    __shared__ int dsts[128];

    const int t = blockIdx.x;
    int rel = -1, base = 0, cnt = 0, accT = 0;
#pragma unroll
    for (int r = 0; r < NREL; ++r) {
        int s = offsets[r], e = offsets[r + 1];
        int nt = (e - s + 127) / 128;
        if (rel < 0 && t < accT + nt) {
            rel = r;
            base = s + (t - accT) * 128;
            cnt = min(128, e - base);
        }
        accT += nt;
    }
    if (rel < 0) return;

    const int tid = threadIdx.x;
    if (tid < 128) {
        int idx = base + tid;
        srcs[tid] = (tid < cnt) ? ssrc[idx] : 0;
        dsts[tid] = (tid < cnt) ? sdst[idx] : 0;
    }
    __syncthreads();

    const unsigned short* WT = WTl + (size_t)rel * DD * DD;
    const int lane = tid & 63;
    const int w = tid >> 6;
    const int wr = w >> 1, wc = w & 1;
    const int n0 = blockIdx.y * 128;
    const int srow = tid >> 2;
    const int sq = tid & 3;

    floatx4 acc[4][4] = {};

    for (int kt = 0; kt < DD / 32; ++kt) {
        const int k0 = kt * 32;
        int r0 = srcs[srow];
        int r1 = srcs[srow + 64];
        GLOAD16(&Xb[(size_t)r0 * DD + k0 + sq * 8], &As[srow][sq * 8]);
        GLOAD16(&Xb[(size_t)r1 * DD + k0 + sq * 8], &As[srow + 64][sq * 8]);
        GLOAD16(&WT[(size_t)(n0 + srow) * DD + k0 + sq * 8], &Bs[srow][sq * 8]);
        GLOAD16(&WT[(size_t)(n0 + srow + 64) * DD + k0 + sq * 8], &Bs[srow + 64][sq * 8]);
        __syncthreads();
        short8 a[4], b[4];
#pragma unroll
        for (int mi = 0; mi < 4; ++mi)
            a[mi] = *(const short8*)&As[wr * 64 + mi * 16 + (lane & 15)][(lane >> 4) * 8];
#pragma unroll
        for (int ni = 0; ni < 4; ++ni)
            b[ni] = *(const short8*)&Bs[wc * 64 + ni * 16 + (lane & 15)][(lane >> 4) * 8];
#pragma unroll
        for (int mi = 0; mi < 4; ++mi)
#pragma unroll
            for (int ni = 0; ni < 4; ++ni)
                acc[mi][ni] = __builtin_amdgcn_mfma_f32_16x16x32_bf16(a[mi], b[ni], acc[mi][ni], 0, 0, 0);
        __syncthreads();
    }

    const int cq = lane >> 4;
    const int cn = lane & 15;
#pragma unroll
    for (int mi = 0; mi < 4; ++mi) {
#pragma unroll
        for (int q = 0; q < 4; ++q) {
            int slot = wr * 64 + mi * 16 + cq * 4 + q;
            if (slot < cnt) {
                int d = dsts[slot];
#pragma unroll
                for (int ni = 0; ni < 4; ++ni) {
                    int col = n0 + wc * 64 + ni * 16 + cn;
                    atomicAdd(&out[(size_t)d * DD + col], acc[mi][ni][q]);
                }
            }
        }
    }
}

extern "C" void kernel_launch(void* const* d_in, const int* in_sizes, int n_in,
                              void* d_out, int out_size, void* d_ws, size_t ws_size,
                              hipStream_t stream)
{
    const float* x      = (const float*)d_in[0];
    const int*   ei     = (const int*)d_in[1];   // [2][NE]
    const int*   et     = (const int*)d_in[2];   // [NE]
    const float* W_rel  = (const float*)d_in[3]; // [NL][NREL][DD][DD]
    const float* W_root = (const float*)d_in[4]; // [NL][DD][DD]
    const float* bias   = (const float*)d_in[5]; // [NL][DD]
    float* out = (float*)d_out;

    unsigned char* wsb = (unsigned char*)d_ws;
    size_t off = 0;
    auto alloc = [&](size_t bytes) -> void* {
        void* p = wsb + off;
        off = (off + bytes + 255) & ~(size_t)255;
        return p;
    };
    unsigned short* xb      = (unsigned short*)alloc((size_t)NN * DD * 2);
    unsigned short* wrelT   = (unsigned short*)alloc((size_t)NL * NREL * DD * DD * 2);
    unsigned short* wrootT  = (unsigned short*)alloc((size_t)NL * DD * DD * 2);
    int* ssrc    = (int*)alloc((size_t)NE * 4);
    int* sdst    = (int*)alloc((size_t)NE * 4);
    int* mpos    = (int*)alloc((size_t)NE * 4);
    int* dstOffs = (int*)alloc((size_t)(NN + 1) * 4);
    int* dstCnt  = (int*)alloc((size_t)NN * 4);
    int* dstCur  = (int*)alloc((size_t)NN * 4);
    int* bktCnt  = (int*)alloc((size_t)NBKT * 4);
    int* bktOff  = (int*)alloc((size_t)(NBKT + 1) * 4);
    int* bktCur  = (int*)alloc((size_t)NBKT * 4);
    int* relOffs = (int*)alloc((size_t)(NREL + 1) * 4);
    int* bktSums = (int*)alloc(256 * 4);
    int* bktBOff = (int*)alloc(256 * 4);
    int* dstSums = (int*)alloc(256 * 4);
    int* dstBOff = (int*)alloc(256 * 4);

    const size_t cap = (ws_size > off) ? ws_size - off : 0;
    const size_t needMsgs = (size_t)NE * DD * 2;   // 128 MB
    const size_t needRoot = (size_t)NN * DD * 2;   // 25.6 MB
    int mode;                  // 1 = msgs path, 0 = atomic fallback
    int useRootB;
    unsigned short* rootb = nullptr;
    unsigned short* msgs = nullptr;
    if (cap >= needMsgs + needRoot + 512) {
        mode = 1; useRootB = 1;
        rootb = (unsigned short*)alloc(needRoot);
        msgs  = (unsigned short*)alloc(needMsgs);
    } else if (cap >= needMsgs) {
        mode = 1; useRootB = 0;
        msgs  = (unsigned short*)alloc(needMsgs);
    } else {
        mode = 0; useRootB = 0;
    }

    const int nbBkt = (NBKT + 1023) / 1024;   // 4
    const int nbDst = (NN + 1023) / 1024;     // 49

    // weights: transpose + bf16
    transpose_bf16<<<dim3(NL * NREL, DD / 32, DD / 32), dim3(32, 8), 0, stream>>>(W_rel, wrelT);
    transpose_bf16<<<dim3(NL, DD / 32, DD / 32), dim3(32, 8), 0, stream>>>(W_root, wrootT);
    conv_bf16<<<2048, 256, 0, stream>>>((const float4*)x, (ushort4*)xb, NN * DD / 4);

    // counting sort by (rel, srcblock), hierarchical scan
    zero_ints<<<(NBKT + 255) / 256, 256, 0, stream>>>(bktCnt, NBKT);
    hist_bkt<<<(NE + 255) / 256, 256, 0, stream>>>(ei, et, bktCnt);
    scan_part<<<nbBkt, 256, 0, stream>>>(bktCnt, NBKT, bktSums);
    scan_tops<<<1, 256, 0, stream>>>(bktSums, nbBkt, bktBOff);
    scan_local<<<nbBkt, 256, 0, stream>>>(bktCnt, NBKT, NE, bktBOff, bktOff, bktCur);
    mk_reloffs<<<1, 64, 0, stream>>>(bktOff, relOffs);
    scatter_bkt<<<(NE + 255) / 256, 256, 0, stream>>>(ei, et, bktCur, ssrc, sdst);

    if (mode == 1) {
        zero_ints<<<(NN + 255) / 256, 256, 0, stream>>>(dstCnt, NN);
        hist_dst<<<(NE + 255) / 256, 256, 0, stream>>>(sdst, dstCnt);
        scan_part<<<nbDst, 256, 0, stream>>>(dstCnt, NN, dstSums);
        scan_tops<<<1, 256, 0, stream>>>(dstSums, nbDst, dstBOff);
        scan_local<<<nbDst, 256, 0, stream>>>(dstCnt, NN, NE, dstBOff, dstOffs, dstCur);
        mk_mpos<<<(NE + 255) / 256, 256, 0, stream>>>(sdst, dstCur, mpos);
    }

    const int ntiles = (NE + 127) / 128 + NREL;              // fallback grid
    const int ntilesI = 8 * ((NE + 127) / 128) + 64;         // XCD-decode upper bound
    const int ncomb = (NN + 3) / 4;

    for (int l = 0; l < NL; ++l) {
        const unsigned short* wl = wrelT + (size_t)l * NREL * DD * DD;
        if (mode == 1) {
            root_gemm_r<<<dim3((NN + 127) / 128, DD / 128), 256, 0, stream>>>(
                xb, wrootT + (size_t)l * DD * DD, bias + (size_t)l * DD, out, rootb, useRootB);
            edge_msgs_m<<<dim3(ntilesI, 2), 256, 0, stream>>>(xb, wl, ssrc, mpos, relOffs, msgs);
            combine4b<<<ncomb, 256, 0, stream>>>(msgs, dstOffs, rootb, out, out, xb,
                                                 useRootB, (l == NL - 1) ? 1 : 0);
        } else {
            root_gemm_r<<<dim3((NN + 127) / 128, DD / 128), 256, 0, stream>>>(
                xb, wrootT + (size_t)l * DD * DD, bias + (size_t)l * DD, out, nullptr, 0);
            edge_gemm_mfma<<<dim3(ntiles, DD / 128), 256, 0, stream>>>(
                xb, wl, ssrc, sdst, relOffs, out);
            relu_convert<<<2048, 256, 0, stream>>>((float4*)out, (ushort4*)xb, NN * DD / 4);
        }
    }
}

// Round 23
// 474.471 us; speedup vs baseline: 1.0370x; 1.0370x over previous
//
#include <hip/hip_runtime.h>

#define NN 50000      // nodes
#define NE 250000     // edges
#define DD 256        // feature dim
#define NREL 8        // relations
#define NL 3          // layers

#define NSRCB ((NN + 127) / 128)     // 391 src blocks
#define NBKT (NREL * NSRCB)          // 3128 sort buckets (rel, src>>7)

typedef __attribute__((ext_vector_type(8))) short short8;
typedef __attribute__((ext_vector_type(4))) float floatx4;
typedef __attribute__((ext_vector_type(2))) unsigned int u32x2;

#if __has_builtin(__builtin_amdgcn_global_load_lds)
#define GLOAD16(g, l) __builtin_amdgcn_global_load_lds( \
    (__attribute__((address_space(1))) void*)(void*)(g), \
    (__attribute__((address_space(3))) void*)(void*)(l), 16, 0, 0)
#else
#define GLOAD16(g, l) do { *(uint4*)(l) = *(const uint4*)(g); } while (0)
#endif

__device__ inline unsigned short f2bf(float f) {
    unsigned int u = __builtin_bit_cast(unsigned int, f);
    u += 0x7FFFu + ((u >> 16) & 1u);          // round-to-nearest-even
    return (unsigned short)(u >> 16);
}
__device__ inline float bf2f(unsigned short u) {
    unsigned int x = ((unsigned int)u) << 16;
    return __builtin_bit_cast(float, x);
}

// ================= sort / index building =================
__global__ void zero_ints(int* __restrict__ p, int n) {
    int i = blockIdx.x * blockDim.x + threadIdx.x;
    if (i < n) p[i] = 0;
}

__global__ void hist_bkt(const int* __restrict__ ei, const int* __restrict__ et,
                         int* __restrict__ bktCnt) {
    int e = blockIdx.x * blockDim.x + threadIdx.x;
    if (e < NE) atomicAdd(&bktCnt[et[e] * NSRCB + (ei[e] >> 7)], 1);
}

// ---- hierarchical exclusive scan: part-sums -> top scan -> local scan ----
__global__ __launch_bounds__(256)
void scan_part(const int* __restrict__ cnt, int n, int* __restrict__ blockSums) {
    __shared__ int ps[256];
    const int b = blockIdx.x, t = threadIdx.x;
    const int base = b * 1024 + t * 4;
    int s = 0;
#pragma unroll
    for (int j = 0; j < 4; ++j) s += (base + j < n) ? cnt[base + j] : 0;
    ps[t] = s;
    __syncthreads();
    for (int o = 128; o > 0; o >>= 1) {
        if (t < o) ps[t] += ps[t + o];
        __syncthreads();
    }
    if (t == 0) blockSums[b] = ps[0];
}

__global__ __launch_bounds__(256)
void scan_tops(const int* __restrict__ blockSums, int nb, int* __restrict__ blockOffs) {
    __shared__ int ps[256];
    const int t = threadIdx.x;
    ps[t] = (t < nb) ? blockSums[t] : 0;
    __syncthreads();
    for (int o = 1; o < 256; o <<= 1) {
        int x = (t >= o) ? ps[t - o] : 0;
        __syncthreads();
        ps[t] += x;
        __syncthreads();
    }
    blockOffs[t] = (t == 0) ? 0 : ps[t - 1];
}

__global__ __launch_bounds__(256)
void scan_local(const int* __restrict__ cnt, int n, int total,
                const int* __restrict__ blockOffs,
                int* __restrict__ offs, int* __restrict__ cur) {
    __shared__ int ps[256];
    const int b = blockIdx.x, t = threadIdx.x;
    const int base = b * 1024 + t * 4;
    int v[4];
#pragma unroll
    for (int j = 0; j < 4; ++j) v[j] = (base + j < n) ? cnt[base + j] : 0;
    int s = v[0] + v[1] + v[2] + v[3];
    ps[t] = s;
    __syncthreads();
    for (int o = 1; o < 256; o <<= 1) {
        int x = (t >= o) ? ps[t - o] : 0;
        __syncthreads();
        ps[t] += x;
        __syncthreads();
    }
    int run = blockOffs[b] + ((t == 0) ? 0 : ps[t - 1]);
#pragma unroll
    for (int j = 0; j < 4; ++j) {
        if (base + j < n) { offs[base + j] = run; cur[base + j] = run; run += v[j]; }
    }
    if (b == 0 && t == 0) offs[n] = total;
}

__global__ void mk_reloffs(const int* __restrict__ bktOff, int* __restrict__ relOffs) {
    const int t = threadIdx.x;
    if (t < NREL) relOffs[t] = bktOff[t * NSRCB];
    if (t == 0) relOffs[NREL] = NE;
}

__global__ void scatter_bkt(const int* __restrict__ ei, const int* __restrict__ et,
                            int* __restrict__ bktCur, int* __restrict__ ssrc,
                            int* __restrict__ sdst) {
    int e = blockIdx.x * blockDim.x + threadIdx.x;
    if (e < NE) {
        int s = ei[e];
        int p = atomicAdd(&bktCur[et[e] * NSRCB + (s >> 7)], 1);
        ssrc[p] = s;
        sdst[p] = ei[NE + e];
    }
}

__global__ void hist_dst(const int* __restrict__ sdst, int* __restrict__ dstCnt) {
    int p = blockIdx.x * blockDim.x + threadIdx.x;
    if (p < NE) atomicAdd(&dstCnt[sdst[p]], 1);
}

// message slot for each sorted edge: its position in dst-sorted order
__global__ void mk_mpos(const int* __restrict__ sdst, int* __restrict__ dstCur,
                        int* __restrict__ mpos) {
    int p = blockIdx.x * blockDim.x + threadIdx.x;
    if (p < NE) mpos[p] = atomicAdd(&dstCur[sdst[p]], 1);
}

// ============ weight transpose + fp32->bf16 (out[m][e][d] = in[m][d][e]) ============
__global__ void transpose_bf16(const float* __restrict__ src, unsigned short* __restrict__ dst) {
    __shared__ float t[32][33];
    const size_t mb = (size_t)blockIdx.x * DD * DD;
    const int d0 = blockIdx.y * 32, e0 = blockIdx.z * 32;
    const int tx = threadIdx.x, ty = threadIdx.y;
#pragma unroll
    for (int i = 0; i < 4; ++i)
        t[ty + 8 * i][tx] = src[mb + (size_t)(d0 + ty + 8 * i) * DD + e0 + tx];
    __syncthreads();
#pragma unroll
    for (int i = 0; i < 4; ++i)
        dst[mb + (size_t)(e0 + ty + 8 * i) * DD + d0 + tx] = f2bf(t[tx][ty + 8 * i]);
}

__global__ void conv_bf16(const float4* __restrict__ s, ushort4* __restrict__ d, int n4) {
    int i = blockIdx.x * blockDim.x + threadIdx.x;
    const int stride = gridDim.x * blockDim.x;
    for (; i < n4; i += stride) {
        float4 v = s[i];
        d[i] = make_ushort4(f2bf(v.x), f2bf(v.y), f2bf(v.z), f2bf(v.w));
    }
}

// fallback-path relu+convert
__global__ void relu_convert(float4* __restrict__ p, ushort4* __restrict__ xb, int n4) {
    int i = blockIdx.x * blockDim.x + threadIdx.x;
    const int stride = gridDim.x * blockDim.x;
    for (; i < n4; i += stride) {
        float4 v = p[i];
        v.x = v.x > 0.f ? v.x : 0.f;
        v.y = v.y > 0.f ? v.y : 0.f;
        v.z = v.z > 0.f ? v.z : 0.f;
        v.w = v.w > 0.f ? v.w : 0.f;
        p[i] = v;
        xb[i] = make_ushort4(f2bf(v.x), f2bf(v.y), f2bf(v.z), f2bf(v.w));
    }
}

// ---- root GEMM (MFMA), r13 row-major LDS staging, bf16 or fp32 epilogue ----
__global__ __launch_bounds__(256)
void root_gemm_r(const unsigned short* __restrict__ Xb, const unsigned short* __restrict__ WT,
                 const float* __restrict__ bias, float* __restrict__ Cf,
                 unsigned short* __restrict__ Cb, int useB)
{
    __shared__ unsigned short As[128][32];
    __shared__ unsigned short Bs[128][32];
    const int tid = threadIdx.x;
    const int lane = tid & 63;
    const int w = tid >> 6;
    const int wr = w >> 1, wc = w & 1;
    const int m0 = blockIdx.x * 128;
    const int n0 = blockIdx.y * 128;
    const int srow = tid >> 2;          // 0..63
    const int sq = tid & 3;             // 16B quarter of 64B k-slice

    floatx4 acc[4][4] = {};

    for (int kt = 0; kt < DD / 32; ++kt) {
        const int k0 = kt * 32;
        int r0 = min(m0 + srow, NN - 1);
        int r1 = min(m0 + srow + 64, NN - 1);
        GLOAD16(&Xb[(size_t)r0 * DD + k0 + sq * 8], &As[srow][sq * 8]);
        GLOAD16(&Xb[(size_t)r1 * DD + k0 + sq * 8], &As[srow + 64][sq * 8]);
        GLOAD16(&WT[(size_t)(n0 + srow) * DD + k0 + sq * 8], &Bs[srow][sq * 8]);
        GLOAD16(&WT[(size_t)(n0 + srow + 64) * DD + k0 + sq * 8], &Bs[srow + 64][sq * 8]);
        __syncthreads();
        short8 a[4], b[4];
#pragma unroll
        for (int mi = 0; mi < 4; ++mi)
            a[mi] = *(const short8*)&As[wr * 64 + mi * 16 + (lane & 15)][(lane >> 4) * 8];
#pragma unroll
        for (int ni = 0; ni < 4; ++ni)
            b[ni] = *(const short8*)&Bs[wc * 64 + ni * 16 + (lane & 15)][(lane >> 4) * 8];
#pragma unroll
        for (int mi = 0; mi < 4; ++mi)
#pragma unroll
            for (int ni = 0; ni < 4; ++ni)
                acc[mi][ni] = __builtin_amdgcn_mfma_f32_16x16x32_bf16(a[mi], b[ni], acc[mi][ni], 0, 0, 0);
        __syncthreads();
    }

    const int cq = lane >> 4;
    const int cn = lane & 15;
#pragma unroll
    for (int mi = 0; mi < 4; ++mi) {
#pragma unroll
        for (int q = 0; q < 4; ++q) {
            int row = m0 + wr * 64 + mi * 16 + cq * 4 + q;
            if (row < NN) {
#pragma unroll
                for (int ni = 0; ni < 4; ++ni) {
                    int col = n0 + wc * 64 + ni * 16 + cn;
                    float val = acc[mi][ni][q] + bias[col];
                    if (useB) Cb[(size_t)row * DD + col] = f2bf(val);
                    else      Cf[(size_t)row * DD + col] = val;
                }
            }
        }
    }
}

// ==== edge GEMM -> bf16 messages at dst-sorted slots (r18-proven best) ====
// XCD-AWARE window mapping: q0 -> rel=(q0>>3)&7, i=((q0>>6)<<3)|(q0&7).
// Dispatch assigns XCD = q0 % 8 = i % 8, so ALL 8 relations of src-window i
// run on the SAME XCD consecutively -> the 64KB X window is fetched into that
// XCD's private L2 once and reused 8x. 256 thr, 128x128 tile, grid y=2.
__global__ __launch_bounds__(256)
void edge_msgs_m(const unsigned short* __restrict__ Xb, const unsigned short* __restrict__ WTl,
                 const int* __restrict__ ssrc, const int* __restrict__ mpos,
                 const int* __restrict__ relOffs, unsigned short* __restrict__ msgs)
{
    __shared__ unsigned short As[128][32];
    __shared__ unsigned short Bs[128][32];
    __shared__ int srcs[128];
    __shared__ int mposs[128];

    const int q0 = blockIdx.x;
    const int rel = (q0 >> 3) & 7;
    const int i = ((q0 >> 6) << 3) | (q0 & 7);
    const int s = relOffs[rel], e = relOffs[rel + 1];
    const int base = s + i * 128;
    if (base >= e) return;
    const int cnt = min(128, e - base);

    const int tid = threadIdx.x;
    if (tid < 128) {
        int idx = base + tid;
        srcs[tid] = (tid < cnt) ? ssrc[idx] : 0;
        mposs[tid] = (tid < cnt) ? mpos[idx] : 0;
    }
    __syncthreads();

    const unsigned short* WT = WTl + (size_t)rel * DD * DD;

    const int lane = tid & 63;
    const int w = tid >> 6;
    const int wr = w >> 1, wc = w & 1;
    const int n0 = blockIdx.y * 128;
    const int srow = tid >> 2;
    const int sq = tid & 3;

    floatx4 acc[4][4] = {};

    for (int kt = 0; kt < DD / 32; ++kt) {
        const int k0 = kt * 32;
        int r0 = srcs[srow];
        int r1 = srcs[srow + 64];
        GLOAD16(&Xb[(size_t)r0 * DD + k0 + sq * 8], &As[srow][sq * 8]);
        GLOAD16(&Xb[(size_t)r1 * DD + k0 + sq * 8], &As[srow + 64][sq * 8]);
        GLOAD16(&WT[(size_t)(n0 + srow) * DD + k0 + sq * 8], &Bs[srow][sq * 8]);
        GLOAD16(&WT[(size_t)(n0 + srow + 64) * DD + k0 + sq * 8], &Bs[srow + 64][sq * 8]);
        __syncthreads();
        short8 a[4], b[4];
#pragma unroll
        for (int mi = 0; mi < 4; ++mi)
            a[mi] = *(const short8*)&As[wr * 64 + mi * 16 + (lane & 15)][(lane >> 4) * 8];
#pragma unroll
        for (int ni = 0; ni < 4; ++ni)
            b[ni] = *(const short8*)&Bs[wc * 64 + ni * 16 + (lane & 15)][(lane >> 4) * 8];
#pragma unroll
        for (int mi = 0; mi < 4; ++mi)
#pragma unroll
            for (int ni = 0; ni < 4; ++ni)
                acc[mi][ni] = __builtin_amdgcn_mfma_f32_16x16x32_bf16(a[mi], b[ni], acc[mi][ni], 0, 0, 0);
        __syncthreads();
    }

    const int cq = lane >> 4;
    const int cn = lane & 15;
#pragma unroll
    for (int mi = 0; mi < 4; ++mi) {
#pragma unroll
        for (int q = 0; q < 4; ++q) {
            int slot = wr * 64 + mi * 16 + cq * 4 + q;
            if (slot < cnt) {
                size_t mrow = (size_t)mposs[slot] * DD + n0 + wc * 64;
#pragma unroll
                for (int ni = 0; ni < 4; ++ni)
                    msgs[mrow + ni * 16 + cn] = f2bf(acc[mi][ni][q]);
            }
        }
    }
}

// ======== combine: relu(rootb + sum msgs[contiguous, nt-streamed]); write xb/out ========
__global__ __launch_bounds__(256)
void combine4b(const unsigned short* __restrict__ msgs, const int* __restrict__ dstOffs,
               const unsigned short* __restrict__ rootb, const float* __restrict__ rootf,
               float* __restrict__ out, unsigned short* __restrict__ xb,
               int useRootB, int last)
{
    int v = blockIdx.x * 4 + (threadIdx.x >> 6);
    if (v >= NN) return;
    const int lane = threadIdx.x & 63;
    const size_t rb = (size_t)v * DD + lane * 4;
    float4 a;
    if (useRootB) {
        u32x2 r = *(const u32x2*)&rootb[rb];
        a.x = bf2f((unsigned short)(r.x & 0xffff));
        a.y = bf2f((unsigned short)(r.x >> 16));
        a.z = bf2f((unsigned short)(r.y & 0xffff));
        a.w = bf2f((unsigned short)(r.y >> 16));
    } else {
        a = *(const float4*)&rootf[rb];
    }
    const int b0 = dstOffs[v], b1 = dstOffs[v + 1];
    for (int k = b0; k < b1; ++k) {
        // non-temporal: msgs is a read-once 128MB stream; keep it out of L2/L3
        u32x2 m = __builtin_nontemporal_load((const u32x2*)&msgs[(size_t)k * DD + lane * 4]);
        a.x += bf2f((unsigned short)(m.x & 0xffff));
        a.y += bf2f((unsigned short)(m.x >> 16));
        a.z += bf2f((unsigned short)(m.y & 0xffff));
        a.w += bf2f((unsigned short)(m.y >> 16));
    }
    a.x = a.x > 0.f ? a.x : 0.f;
    a.y = a.y > 0.f ? a.y : 0.f;
    a.z = a.z > 0.f ? a.z : 0.f;
    a.w = a.w > 0.f ? a.w : 0.f;
    if (last) {
        *(float4*)&out[rb] = a;
    } else {
        *(ushort4*)&xb[rb] = make_ushort4(f2bf(a.x), f2bf(a.y), f2bf(a.z), f2bf(a.w));
    }
}

// ======== fallback: atomic-scatter edge GEMM (round-5 proven) ========
__global__ __launch_bounds__(256)
void edge_gemm_mfma(const unsigned short* __restrict__ Xb, const unsigned short* __restrict__ WTl,
                    const int* __restrict__ ssrc, const int* __restrict__ sdst,
                    const int* __restrict__ offsets, float* __restrict__ out)
{
    __shared__ unsigned short As[128][32];
    __shared__ unsigned short Bs[128][32];
    __shared__ int srcs[128];
    __shared__ int dsts[128];

    const int t = blockIdx.x;
    int rel = -1, base = 0, cnt = 0, accT = 0;
#pragma unroll
    for (int r = 0; r < NREL; ++r) {
        int s = offsets[r], e = offsets[r + 1];
        int nt = (e - s + 127) / 128;
        if (rel < 0 && t < accT + nt) {
            rel = r;
            base = s + (t - accT) * 128;
            cnt = min(128, e - base);
        }
        accT += nt;
    }
    if (rel < 0) return;

    const int tid = threadIdx.x;
    if (tid < 128) {
        int idx = base + tid;
        srcs[tid] = (tid < cnt) ? ssrc[idx] : 0;
        dsts[tid] = (tid < cnt) ? sdst[idx] : 0;
    }
    __syncthreads();

    const unsigned short* WT = WTl + (size_t)rel * DD * DD;
    const int lane = tid & 63;
    const int w = tid >> 6;
    const int wr = w >> 1, wc = w & 1;
    const int n0 = blockIdx.y * 128;
    const int srow = tid >> 2;
    const int sq = tid & 3;

    floatx4 acc[4][4] = {};

    for (int kt = 0; kt < DD / 32; ++kt) {
        const int k0 = kt * 32;
        int r0 = srcs[srow];
        int r1 = srcs[srow + 64];
        GLOAD16(&Xb[(size_t)r0 * DD + k0 + sq * 8], &As[srow][sq * 8]);
        GLOAD16(&Xb[(size_t)r1 * DD + k0 + sq * 8], &As[srow + 64][sq * 8]);
        GLOAD16(&WT[(size_t)(n0 + srow) * DD + k0 + sq * 8], &Bs[srow][sq * 8]);
        GLOAD16(&WT[(size_t)(n0 + srow + 64) * DD + k0 + sq * 8], &Bs[srow + 64][sq * 8]);
        __syncthreads();
        short8 a[4], b[4];
#pragma unroll
        for (int mi = 0; mi < 4; ++mi)
            a[mi] = *(const short8*)&As[wr * 64 + mi * 16 + (lane & 15)][(lane >> 4) * 8];
#pragma unroll
        for (int ni = 0; ni < 4; ++ni)
            b[ni] = *(const short8*)&Bs[wc * 64 + ni * 16 + (lane & 15)][(lane >> 4) * 8];
#pragma unroll
        for (int mi = 0; mi < 4; ++mi)
#pragma unroll
            for (int ni = 0; ni < 4; ++ni)
                acc[mi][ni] = __builtin_amdgcn_mfma_f32_16x16x32_bf16(a[mi], b[ni], acc[mi][ni], 0, 0, 0);
        __syncthreads();
    }

    const int cq = lane >> 4;
    const int cn = lane & 15;
#pragma unroll
    for (int mi = 0; mi < 4; ++mi) {
#pragma unroll
        for (int q = 0; q < 4; ++q) {
            int slot = wr * 64 + mi * 16 + cq * 4 + q;
            if (slot < cnt) {
                int d = dsts[slot];
#pragma unroll
                for (int ni = 0; ni < 4; ++ni) {
                    int col = n0 + wc * 64 + ni * 16 + cn;
                    atomicAdd(&out[(size_t)d * DD + col], acc[mi][ni][q]);
                }
            }
        }
    }
}

extern "C" void kernel_launch(void* const* d_in, const int* in_sizes, int n_in,
                              void* d_out, int out_size, void* d_ws, size_t ws_size,
                              hipStream_t stream)
{
    const float* x      = (const float*)d_in[0];
    const int*   ei     = (const int*)d_in[1];   // [2][NE]
    const int*   et     = (const int*)d_in[2];   // [NE]
    const float* W_rel  = (const float*)d_in[3]; // [NL][NREL][DD][DD]
    const float* W_root = (const float*)d_in[4]; // [NL][DD][DD]
    const float* bias   = (const float*)d_in[5]; // [NL][DD]
    float* out = (float*)d_out;

    unsigned char* wsb = (unsigned char*)d_ws;
    size_t off = 0;
    auto alloc = [&](size_t bytes) -> void* {
        void* p = wsb + off;
        off = (off + bytes + 255) & ~(size_t)255;
        return p;
    };
    unsigned short* xb      = (unsigned short*)alloc((size_t)NN * DD * 2);
    unsigned short* wrelT   = (unsigned short*)alloc((size_t)NL * NREL * DD * DD * 2);
    unsigned short* wrootT  = (unsigned short*)alloc((size_t)NL * DD * DD * 2);
    int* ssrc    = (int*)alloc((size_t)NE * 4);
    int* sdst    = (int*)alloc((size_t)NE * 4);
    int* mpos    = (int*)alloc((size_t)NE * 4);
    int* dstOffs = (int*)alloc((size_t)(NN + 1) * 4);
    int* dstCnt  = (int*)alloc((size_t)NN * 4);
    int* dstCur  = (int*)alloc((size_t)NN * 4);
    int* bktCnt  = (int*)alloc((size_t)NBKT * 4);
    int* bktOff  = (int*)alloc((size_t)(NBKT + 1) * 4);
    int* bktCur  = (int*)alloc((size_t)NBKT * 4);
    int* relOffs = (int*)alloc((size_t)(NREL + 1) * 4);
    int* bktSums = (int*)alloc(256 * 4);
    int* bktBOff = (int*)alloc(256 * 4);
    int* dstSums = (int*)alloc(256 * 4);
    int* dstBOff = (int*)alloc(256 * 4);

    const size_t cap = (ws_size > off) ? ws_size - off : 0;
    const size_t needMsgs = (size_t)NE * DD * 2;   // 128 MB
    const size_t needRoot = (size_t)NN * DD * 2;   // 25.6 MB
    int mode;                  // 1 = msgs path, 0 = atomic fallback
    int useRootB;
    unsigned short* rootb = nullptr;
    unsigned short* msgs = nullptr;
    if (cap >= needMsgs + needRoot + 512) {
        mode = 1; useRootB = 1;
        rootb = (unsigned short*)alloc(needRoot);
        msgs  = (unsigned short*)alloc(needMsgs);
    } else if (cap >= needMsgs) {
        mode = 1; useRootB = 0;
        msgs  = (unsigned short*)alloc(needMsgs);
    } else {
        mode = 0; useRootB = 0;
    }

    const int nbBkt = (NBKT + 1023) / 1024;   // 4
    const int nbDst = (NN + 1023) / 1024;     // 49

    // weights: transpose + bf16
    transpose_bf16<<<dim3(NL * NREL, DD / 32, DD / 32), dim3(32, 8), 0, stream>>>(W_rel, wrelT);
    transpose_bf16<<<dim3(NL, DD / 32, DD / 32), dim3(32, 8), 0, stream>>>(W_root, wrootT);
    conv_bf16<<<2048, 256, 0, stream>>>((const float4*)x, (ushort4*)xb, NN * DD / 4);

    // counting sort by (rel, srcblock), hierarchical scan
    zero_ints<<<(NBKT + 255) / 256, 256, 0, stream>>>(bktCnt, NBKT);
    hist_bkt<<<(NE + 255) / 256, 256, 0, stream>>>(ei, et, bktCnt);
    scan_part<<<nbBkt, 256, 0, stream>>>(bktCnt, NBKT, bktSums);
    scan_tops<<<1, 256, 0, stream>>>(bktSums, nbBkt, bktBOff);
    scan_local<<<nbBkt, 256, 0, stream>>>(bktCnt, NBKT, NE, bktBOff, bktOff, bktCur);
    mk_reloffs<<<1, 64, 0, stream>>>(bktOff, relOffs);
    scatter_bkt<<<(NE + 255) / 256, 256, 0, stream>>>(ei, et, bktCur, ssrc, sdst);

    if (mode == 1) {
        zero_ints<<<(NN + 255) / 256, 256, 0, stream>>>(dstCnt, NN);
        hist_dst<<<(NE + 255) / 256, 256, 0, stream>>>(sdst, dstCnt);
        scan_part<<<nbDst, 256, 0, stream>>>(dstCnt, NN, dstSums);
        scan_tops<<<1, 256, 0, stream>>>(dstSums, nbDst, dstBOff);
        scan_local<<<nbDst, 256, 0, stream>>>(dstCnt, NN, NE, dstBOff, dstOffs, dstCur);
        mk_mpos<<<(NE + 255) / 256, 256, 0, stream>>>(sdst, dstCur, mpos);
    }

    const int ntiles = (NE + 127) / 128 + NREL;              // fallback grid
    const int ntilesI = 8 * ((NE + 127) / 128) + 64;         // XCD-decode upper bound
    const int ncomb = (NN + 3) / 4;

    for (int l = 0; l < NL; ++l) {
        const unsigned short* wl = wrelT + (size_t)l * NREL * DD * DD;
        if (mode == 1) {
            root_gemm_r<<<dim3((NN + 127) / 128, DD / 128), 256, 0, stream>>>(
                xb, wrootT + (size_t)l * DD * DD, bias + (size_t)l * DD, out, rootb, useRootB);
            edge_msgs_m<<<dim3(ntilesI, 2), 256, 0, stream>>>(xb, wl, ssrc, mpos, relOffs, msgs);
            combine4b<<<ncomb, 256, 0, stream>>>(msgs, dstOffs, rootb, out, out, xb,
                                                 useRootB, (l == NL - 1) ? 1 : 0);
        } else {
            root_gemm_r<<<dim3((NN + 127) / 128, DD / 128), 256, 0, stream>>>(
                xb, wrootT + (size_t)l * DD * DD, bias + (size_t)l * DD, out, nullptr, 0);
            edge_gemm_mfma<<<dim3(ntiles, DD / 128), 256, 0, stream>>>(
                xb, wl, ssrc, sdst, relOffs, out);
            relu_convert<<<2048, 256, 0, stream>>>((float4*)out, (ushort4*)xb, NN * DD / 4);
        }
    }
}